// Round 1
// baseline (617.409 us; speedup 1.0000x reference)
//
#include <hip/hip_runtime.h>

typedef _Float16 h16;
typedef _Float16 h8 __attribute__((ext_vector_type(8)));
typedef float f4 __attribute__((ext_vector_type(4)));

#define NB 8192
#define NENC 4096
#define NH 128
#define NL 10
#define NT 12

// ---- workspace layout (element offsets in halfs unless noted) ----
#define OFF_FCIN 0                    // packed fc_in_W  [128 x 4096] fp16
#define SZ_FCIN (128*4096)
#define OFF_W (OFF_FCIN + SZ_FCIN)    // packed Wih/Whh  [10][2][512 x 128] fp16
#define SZ_W (10*2*512*128)
#define OFF_FCOUT (OFF_W + SZ_W)      // packed fc_out_W [80 x 128] fp16 (rows 75..79 zero)
#define SZ_FCOUT (80*128)
#define OFF_ENC (OFF_FCOUT + SZ_FCOUT) // enc (relu(fc_in)) [8192 x 128] fp16
#define SZ_ENC (8192*128)
#define BYTE_BIAS ((OFF_ENC + SZ_ENC)*2) // combined bias [10][512] f32 (byte offset)
// total ws usage: 5,808,128 bytes

__device__ __forceinline__ float sigf(float x) {
  float e = __builtin_amdgcn_exp2f(-1.4426950408889634f * x);
  return __builtin_amdgcn_rcpf(1.0f + e);
}
__device__ __forceinline__ float tanhf_(float x) {
  float e = __builtin_amdgcn_exp2f(-2.8853900817779268f * x);
  return 2.0f * __builtin_amdgcn_rcpf(1.0f + e) - 1.0f;
}
__device__ __forceinline__ f4 splat4(float v) { f4 r; r[0]=v; r[1]=v; r[2]=v; r[3]=v; return r; }

// Pack B-operand matrices [R rows=output cols][K] into MFMA-fragment order:
// fragment load for (16-row tile rt, 8-k group k8) = contiguous 16B at
// ((rt)*(K/8)+k8)*128 + (r&15)*16 bytes -> lanes fully coalesced.
__device__ __forceinline__ int packidx(int r, int k, int Kd8) {
  return ((r >> 4) * Kd8 + (k >> 3)) * 128 + ((r & 15) << 3) + (k & 7);
}

// ---------------- prep: convert + pack weights, combine biases ----------------
__global__ __launch_bounds__(256) void prep(const float* __restrict__ fcinW,
                                            const float* __restrict__ Wih,
                                            const float* __restrict__ Whh,
                                            const float* __restrict__ bih,
                                            const float* __restrict__ bhh,
                                            const float* __restrict__ fcoutW,
                                            h16* __restrict__ wsh,
                                            float* __restrict__ wbias) {
  int idx = blockIdx.x * 256 + threadIdx.x;
  if (idx < 524288) {                         // fc_in_W [128][4096]
    int r = idx >> 12, k = idx & 4095;
    wsh[OFF_FCIN + packidx(r, k, 512)] = (h16)fcinW[idx];
  } else if (idx < 524288 + 1310720) {        // Wih/Whh [10][512][128]
    int rel = idx - 524288;
    int l = rel / 131072; int rr = rel % 131072;
    int ssel = rr >> 16; int rk = rr & 65535;
    int r = rk >> 7, k = rk & 127;
    float v = ssel ? Whh[l * 65536 + rk] : Wih[l * 65536 + rk];
    wsh[OFF_W + (l * 2 + ssel) * 65536 + packidx(r, k, 16)] = (h16)v;
  } else if (idx < 524288 + 1310720 + 10240) { // fc_out_W padded to [80][128]
    int rel = idx - (524288 + 1310720);
    int r = rel >> 7, k = rel & 127;
    float v = (r < 75) ? fcoutW[r * 128 + k] : 0.0f;
    wsh[OFF_FCOUT + packidx(r, k, 16)] = (h16)v;
  } else if (idx < 524288 + 1310720 + 10240 + 5120) {
    int rel = idx - (524288 + 1310720 + 10240);
    wbias[rel] = bih[rel] + bhh[rel];
  }
}

// ---------------- fc_in GEMM: enc = relu(A @ W^T + b), fp16 out ----------------
// grid 512 (16 rows each), block 256 (4 waves x 32 cols). Memory-bound on the
// 134 MB f32 A read; fragments loaded straight from global (no LDS needed).
__global__ __launch_bounds__(256) void kin(const float* __restrict__ A,
                                           const float* __restrict__ bvec,
                                           h16* __restrict__ wsh) {
  const h16* Wp = wsh + OFF_FCIN;
  h16* ench = wsh + OFF_ENC;
  int tid = threadIdx.x;
  int w = tid >> 6, lane = tid & 63, s = lane & 15, q = lane >> 4;
  int m0 = blockIdx.x * 16;
  int c0 = w * 32 + s, c1 = c0 + 16;
  f4 acc0 = splat4(bvec[c0]);
  f4 acc1 = splat4(bvec[c1]);
  const float* arow = A + (size_t)(m0 + s) * NENC;
  const h16* wp0 = Wp + (w * 2 + 0) * (512 * 128) + s * 8;
  const h16* wp1 = Wp + (w * 2 + 1) * (512 * 128) + s * 8;
#pragma unroll 4
  for (int kb = 0; kb < 128; ++kb) {
    int k0 = kb * 32 + q * 8;
    float4 x0 = *(const float4*)(arow + k0);
    float4 x1 = *(const float4*)(arow + k0 + 4);
    h8 af;
    af[0] = (h16)x0.x; af[1] = (h16)x0.y; af[2] = (h16)x0.z; af[3] = (h16)x0.w;
    af[4] = (h16)x1.x; af[5] = (h16)x1.y; af[6] = (h16)x1.z; af[7] = (h16)x1.w;
    h8 b0 = *(const h8*)(wp0 + (kb * 4 + q) * 128);
    h8 b1 = *(const h8*)(wp1 + (kb * 4 + q) * 128);
    acc0 = __builtin_amdgcn_mfma_f32_16x16x32_f16(af, b0, acc0, 0, 0, 0);
    acc1 = __builtin_amdgcn_mfma_f32_16x16x32_f16(af, b1, acc1, 0, 0, 0);
  }
#pragma unroll
  for (int r = 0; r < 4; ++r) {
    int b = m0 + q * 4 + r;
    float v0 = acc0[r]; v0 = v0 > 0.f ? v0 : 0.f;
    float v1 = acc1[r]; v1 = v1 > 0.f ? v1 : 0.f;
    ench[(size_t)b * NH + c0] = (h16)v0;
    ench[(size_t)b * NH + c1] = (h16)v1;
  }
}

// ---------------- persistent LSTM + output head ----------------
// grid 256 = 1 WG/CU, 32 batch rows each. Layers outer, time inner; weight
// B-fragments VGPR-resident per layer (loaded once per layer, reused 12 t's).
// Wave w owns units [32w,32w+32): gate cols {g*128+32w..+32} for g=i,f,g,o, so
// the c/h update is lane-local. x[t] and h ping-pong live in LDS (pad 136).
__global__ __launch_bounds__(256, 1) void lstm(h16* __restrict__ wsh,
                                               const float* __restrict__ wbias,
                                               const float* __restrict__ fcoutb,
                                               float* __restrict__ out) {
  __shared__ h16 xbuf[NT][32][136];   // 104448 B
  __shared__ h16 hbuf[2][32][136];    // 17408 B  (re-used as f32 softmax stage)
  int tid = threadIdx.x;
  int w = tid >> 6, lane = tid & 63, s = lane & 15, q = lane >> 4;
  int brow = blockIdx.x * 32;
  const h16* ench = wsh + OFF_ENC;
  {  // x[t] = enc for all t (layer-0 input is the repeated encoding)
    int r = tid >> 3, cg = (tid & 7) * 16;
    h8 e0 = *(const h8*)(ench + (size_t)(brow + r) * NH + cg);
    h8 e1 = *(const h8*)(ench + (size_t)(brow + r) * NH + cg + 8);
    for (int t = 0; t < NT; ++t) {
      *(h8*)&xbuf[t][r][cg] = e0;
      *(h8*)&xbuf[t][r][cg + 8] = e1;
    }
  }
  h8 wx[4][2][4], wh[4][2][4];   // [gate][unit-chunk][ktile] B-frags, 256 VGPRs
  float bb[4][2];
  float c[2][2][4];              // [mtile][unit-chunk][row-reg]
  for (int l = 0; l < NL; ++l) {
    const h16* wih = wsh + OFF_W + (l * 2 + 0) * 65536;
    const h16* whh = wsh + OFF_W + (l * 2 + 1) * 65536;
#pragma unroll
    for (int g = 0; g < 4; ++g)
#pragma unroll
      for (int uc = 0; uc < 2; ++uc) {
        int rb = g * 8 + w * 2 + uc;
#pragma unroll
        for (int kt = 0; kt < 4; ++kt) {
          int off = (rb * 16 + kt * 4 + q) * 128 + s * 8;
          wx[g][uc][kt] = *(const h8*)(wih + off);
          wh[g][uc][kt] = *(const h8*)(whh + off);
        }
        bb[g][uc] = wbias[l * 512 + g * 128 + w * 32 + uc * 16 + s];
      }
#pragma unroll
    for (int mt = 0; mt < 2; ++mt)
#pragma unroll
      for (int uc = 0; uc < 2; ++uc)
#pragma unroll
        for (int r = 0; r < 4; ++r) c[mt][uc][r] = 0.f;
    for (int j = tid; j < 32 * 136; j += 256) hbuf[0][0][j] = (h16)0.f;
    __syncthreads();
    for (int t = 0; t < NT; ++t) {
      int cur = t & 1, nxt = cur ^ 1;
      h8 ax[2][4], ah[2][4];
#pragma unroll
      for (int mt = 0; mt < 2; ++mt)
#pragma unroll
        for (int kt = 0; kt < 4; ++kt) {
          ax[mt][kt] = *(const h8*)&xbuf[t][mt * 16 + s][kt * 32 + q * 8];
          ah[mt][kt] = *(const h8*)&hbuf[cur][mt * 16 + s][kt * 32 + q * 8];
        }
      __syncthreads();  // all frag reads done before anyone overwrites x[t]/h
#pragma unroll
      for (int mt = 0; mt < 2; ++mt) {
        f4 acc[4][2];
#pragma unroll
        for (int g = 0; g < 4; ++g)
#pragma unroll
          for (int uc = 0; uc < 2; ++uc) {
            f4 a = splat4(bb[g][uc]);
#pragma unroll
            for (int kt = 0; kt < 4; ++kt) {
              a = __builtin_amdgcn_mfma_f32_16x16x32_f16(ax[mt][kt], wx[g][uc][kt], a, 0, 0, 0);
              a = __builtin_amdgcn_mfma_f32_16x16x32_f16(ah[mt][kt], wh[g][uc][kt], a, 0, 0, 0);
            }
            acc[g][uc] = a;
          }
#pragma unroll
        for (int uc = 0; uc < 2; ++uc)
#pragma unroll
          for (int r = 0; r < 4; ++r) {
            float iv = acc[0][uc][r], fv = acc[1][uc][r];
            float gv = acc[2][uc][r], ov = acc[3][uc][r];
            float cc = sigf(fv) * c[mt][uc][r] + sigf(iv) * tanhf_(gv);
            c[mt][uc][r] = cc;
            float hv = sigf(ov) * tanhf_(cc);
            int row = mt * 16 + q * 4 + r, col = w * 32 + uc * 16 + s;
            h16 hx = (h16)hv;
            hbuf[nxt][row][col] = hx;   // h for t+1
            xbuf[t][row][col] = hx;     // x[t] for layer l+1
          }
      }
      __syncthreads();
    }
  }
  // ---- output head: fc = y @ fc_out_W^T + b; each wave takes 3 timesteps ----
  h8 wo[5][4];
  float bo[5];
  const h16* fco = wsh + OFF_FCOUT;
#pragma unroll
  for (int nt = 0; nt < 5; ++nt) {
#pragma unroll
    for (int kt = 0; kt < 4; ++kt)
      wo[nt][kt] = *(const h8*)(fco + (nt * 16 + kt * 4 + q) * 128 + s * 8);
    int col = nt * 16 + s;
    bo[nt] = (col < 75) ? fcoutb[col] : 0.f;
  }
  float* probst = (float*)&hbuf[0][0][0];  // [32][26] f32 stage (hbuf is dead)
  for (int tt = 0; tt < 3; ++tt) {
    int t = w * 3 + tt;
    h8 ax[2][4];
#pragma unroll
    for (int mt = 0; mt < 2; ++mt)
#pragma unroll
      for (int kt = 0; kt < 4; ++kt)
        ax[mt][kt] = *(const h8*)&xbuf[t][mt * 16 + s][kt * 32 + q * 8];
#pragma unroll
    for (int mt = 0; mt < 2; ++mt)
#pragma unroll
      for (int nt = 0; nt < 5; ++nt) {
        f4 a = splat4(bo[nt]);
#pragma unroll
        for (int kt = 0; kt < 4; ++kt)
          a = __builtin_amdgcn_mfma_f32_16x16x32_f16(ax[mt][kt], wo[nt][kt], a, 0, 0, 0);
        int col = nt * 16 + s;
#pragma unroll
        for (int r = 0; r < 4; ++r) {
          int row = mt * 16 + q * 4 + r;
          int b = brow + row;
          float v = a[r];
          // predictions[b][m][t][xy], m=col/2, xy=col&1 (cols 0..49)
          if (col < 50)
            out[(size_t)b * 600 + (col >> 1) * 24 + t * 2 + (col & 1)] = v;
          if (t == 11 && col >= 50 && col < 75)
            probst[row * 26 + (col - 50)] = v;
        }
      }
  }
  __syncthreads();
  if (tid < 32) {  // softmax over 25 modes, one row per thread
    float vals[25];
    float m = -1e30f;
#pragma unroll
    for (int j = 0; j < 25; ++j) { vals[j] = probst[tid * 26 + j]; m = vals[j] > m ? vals[j] : m; }
    float sum = 0.f;
#pragma unroll
    for (int j = 0; j < 25; ++j) {
      float e = __builtin_amdgcn_exp2f((vals[j] - m) * 1.4426950408889634f);
      vals[j] = e; sum += e;
    }
    float rs = 1.0f / sum;
    size_t pb = (size_t)4915200 + (size_t)(brow + tid) * 25;
#pragma unroll
    for (int j = 0; j < 25; ++j) out[pb + j] = vals[j] * rs;
  }
}

extern "C" void kernel_launch(void* const* d_in, const int* in_sizes, int n_in,
                              void* d_out, int out_size, void* d_ws, size_t ws_size,
                              hipStream_t stream) {
  const float* backbone = (const float*)d_in[0];
  const float* fcinW    = (const float*)d_in[1];
  const float* fcinb    = (const float*)d_in[2];
  const float* Wih      = (const float*)d_in[3];
  const float* Whh      = (const float*)d_in[4];
  const float* bih      = (const float*)d_in[5];
  const float* bhh      = (const float*)d_in[6];
  const float* fcoutW   = (const float*)d_in[7];
  const float* fcoutb   = (const float*)d_in[8];
  h16* wsh = (h16*)d_ws;
  float* wbias = (float*)((char*)d_ws + BYTE_BIAS);

  prep<<<7228, 256, 0, stream>>>(fcinW, Wih, Whh, bih, bhh, fcoutW, wsh, wbias);
  kin<<<512, 256, 0, stream>>>(backbone, fcinb, wsh);
  lstm<<<256, 256, 0, stream>>>(wsh, wbias, fcoutb, (float*)d_out);
}

// Round 2
// 541.561 us; speedup vs baseline: 1.1401x; 1.1401x over previous
//
#include <hip/hip_runtime.h>

typedef _Float16 h16;
typedef _Float16 h8 __attribute__((ext_vector_type(8)));
typedef float f4 __attribute__((ext_vector_type(4)));

#define NB 8192
#define NENC 4096
#define NH 128
#define NL 10
#define NT 12

// ---- workspace layout (element offsets in halfs unless noted) ----
#define OFF_FCIN 0                    // packed fc_in_W  [128 x 4096] fp16
#define SZ_FCIN (128*4096)
#define OFF_W (OFF_FCIN + SZ_FCIN)    // packed Wih/Whh  [10][2][512 x 128] fp16
#define SZ_W (10*2*512*128)
#define OFF_FCOUT (OFF_W + SZ_W)      // packed fc_out_W [80 x 128] fp16 (rows 75..79 zero)
#define SZ_FCOUT (80*128)
#define OFF_ENC (OFF_FCOUT + SZ_FCOUT) // enc (relu(fc_in)) [8192 x 128] fp16
#define SZ_ENC (8192*128)
#define BYTE_BIAS ((OFF_ENC + SZ_ENC)*2) // combined bias [10][512] f32 (byte offset)

__device__ __forceinline__ float sigf(float x) {
  float e = __builtin_amdgcn_exp2f(-1.4426950408889634f * x);
  return __builtin_amdgcn_rcpf(1.0f + e);
}
__device__ __forceinline__ float tanhf_(float x) {
  float e = __builtin_amdgcn_exp2f(-2.8853900817779268f * x);
  return 2.0f * __builtin_amdgcn_rcpf(1.0f + e) - 1.0f;
}
__device__ __forceinline__ f4 splat4(float v) { f4 r; r[0]=v; r[1]=v; r[2]=v; r[3]=v; return r; }
__device__ __forceinline__ h8 cvt8(float4 a, float4 b) {
  h8 r; r[0]=(h16)a.x; r[1]=(h16)a.y; r[2]=(h16)a.z; r[3]=(h16)a.w;
  r[4]=(h16)b.x; r[5]=(h16)b.y; r[6]=(h16)b.z; r[7]=(h16)b.w; return r;
}

// ---------------- prep: convert + pack weights (8 elems/thread, vectorized) ----
// Pack B-operand [R rows][K] so the frag for (rowtile rt, k8) is 16 contiguous
// bytes per lane: dst = ((rt*Kd8 + k8)*128 + (r&15)*8). float4 x2 in, h8 out.
__global__ __launch_bounds__(256) void prep(const float* __restrict__ fcinW,
                                            const float* __restrict__ Wih,
                                            const float* __restrict__ Whh,
                                            const float* __restrict__ bih,
                                            const float* __restrict__ bhh,
                                            const float* __restrict__ fcoutW,
                                            h16* __restrict__ wsh,
                                            float* __restrict__ wbias) {
  int idx = blockIdx.x * 256 + threadIdx.x;
  if (idx < 65536) {                          // fc_in_W [128][4096], Kd8=512
    int r = idx >> 9, k8 = idx & 511;
    const float* src = fcinW + r * 4096 + k8 * 8;
    h8 v = cvt8(*(const float4*)src, *(const float4*)(src + 4));
    *(h8*)(wsh + OFF_FCIN + (((r >> 4) * 512 + k8) * 128 + (r & 15) * 8)) = v;
  } else if (idx < 229376) {                  // Wih/Whh [10][512][128], Kd8=16
    int rel = idx - 65536;
    int l = rel >> 14, rr = rel & 16383;
    int ssel = rr >> 13, rk8 = rr & 8191;
    int r = rk8 >> 4, k8 = rk8 & 15;
    const float* src = (ssel ? Whh : Wih) + l * 65536 + r * 128 + k8 * 8;
    h8 v = cvt8(*(const float4*)src, *(const float4*)(src + 4));
    *(h8*)(wsh + OFF_W + (l * 2 + ssel) * 65536 +
           (((r >> 4) * 16 + k8) * 128 + (r & 15) * 8)) = v;
  } else if (idx < 230656) {                  // fc_out_W padded to [80][128]
    int rel = idx - 229376;
    int r = rel >> 4, k8 = rel & 15;
    h8 v;
    if (r < 75) {
      const float* src = fcoutW + r * 128 + k8 * 8;
      v = cvt8(*(const float4*)src, *(const float4*)(src + 4));
    } else {
      for (int j = 0; j < 8; ++j) v[j] = (h16)0.f;
    }
    *(h8*)(wsh + OFF_FCOUT + (((r >> 4) * 16 + k8) * 128 + (r & 15) * 8)) = v;
  } else if (idx < 235776) {
    int rel = idx - 230656;
    wbias[rel] = bih[rel] + bhh[rel];
  }
}

// ---------------- fc_in GEMM: enc = relu(A @ W^T + b), fp16 out ----------------
// grid 512 (16 rows each), block 256 (4 waves x 32 cols). x0+x1 together cover
// 128 contiguous bytes per A-row per iter -> full cache-line use.
__global__ __launch_bounds__(256) void kin(const float* __restrict__ A,
                                           const float* __restrict__ bvec,
                                           h16* __restrict__ wsh) {
  const h16* Wp = wsh + OFF_FCIN;
  h16* ench = wsh + OFF_ENC;
  int tid = threadIdx.x;
  int w = tid >> 6, lane = tid & 63, s = lane & 15, q = lane >> 4;
  int m0 = blockIdx.x * 16;
  int c0 = w * 32 + s, c1 = c0 + 16;
  f4 acc0 = splat4(bvec[c0]);
  f4 acc1 = splat4(bvec[c1]);
  const float* arow = A + (size_t)(m0 + s) * NENC;
  const h16* wp0 = Wp + (w * 2 + 0) * (512 * 128) + s * 8;
  const h16* wp1 = Wp + (w * 2 + 1) * (512 * 128) + s * 8;
#pragma unroll 4
  for (int kb = 0; kb < 128; ++kb) {
    int k0 = kb * 32 + q * 8;
    float4 x0 = *(const float4*)(arow + k0);
    float4 x1 = *(const float4*)(arow + k0 + 4);
    h8 af = cvt8(x0, x1);
    h8 b0 = *(const h8*)(wp0 + (kb * 4 + q) * 128);
    h8 b1 = *(const h8*)(wp1 + (kb * 4 + q) * 128);
    acc0 = __builtin_amdgcn_mfma_f32_16x16x32_f16(af, b0, acc0, 0, 0, 0);
    acc1 = __builtin_amdgcn_mfma_f32_16x16x32_f16(af, b1, acc1, 0, 0, 0);
  }
#pragma unroll
  for (int r = 0; r < 4; ++r) {
    int b = m0 + q * 4 + r;
    float v0 = acc0[r]; v0 = v0 > 0.f ? v0 : 0.f;
    float v1 = acc1[r]; v1 = v1 > 0.f ? v1 : 0.f;
    ench[(size_t)b * NH + c0] = (h16)v0;
    ench[(size_t)b * NH + c1] = (h16)v1;
  }
}

// ---------------- persistent LSTM + output head ----------------
// grid 256 = 1 WG/CU, block 512 = 8 waves (2/SIMD). 32 batch rows per WG.
// Each wave owns 16 unit-cols -> weight frags = 32 h8 = 128 VGPRs (was 256,
// which blew the register budget and serialized the MFMA chains in R1).
// Layers outer, time inner; x[t]/h ping-pong in LDS (pad 136 halfs).
__global__ __launch_bounds__(512, 2) void lstm(h16* __restrict__ wsh,
                                               const float* __restrict__ wbias,
                                               const float* __restrict__ fcoutb,
                                               float* __restrict__ out) {
  __shared__ h16 xbuf[NT][32][136];   // 104448 B
  __shared__ h16 hbuf[2][32][136];    // 17408 B (reused as f32 softmax stage)
  int tid = threadIdx.x;
  int w = tid >> 6, lane = tid & 63, s = lane & 15, q = lane >> 4;
  int brow = blockIdx.x * 32;
  const h16* ench = wsh + OFF_ENC;
  {  // x[t] = enc for all t
    int r = tid >> 4, cg = (tid & 15) * 8;
    h8 e = *(const h8*)(ench + (size_t)(brow + r) * NH + cg);
#pragma unroll
    for (int t = 0; t < NT; ++t) *(h8*)&xbuf[t][r][cg] = e;
  }
  h8 wx[4][4], wh[4][4];   // [gate][ktile] B-frags: 128 VGPRs
  float bb[4];
  float c[2][4];           // [mtile][row-reg]
  for (int l = 0; l < NL; ++l) {
    const h16* wih = wsh + OFF_W + (l * 2 + 0) * 65536;
    const h16* whh = wsh + OFF_W + (l * 2 + 1) * 65536;
#pragma unroll
    for (int g = 0; g < 4; ++g) {
#pragma unroll
      for (int kt = 0; kt < 4; ++kt) {
        int off = (((g * 8 + w) * 16 + kt * 4 + q) * 128) + s * 8;
        wx[g][kt] = *(const h8*)(wih + off);
        wh[g][kt] = *(const h8*)(whh + off);
      }
      bb[g] = wbias[l * 512 + g * 128 + w * 16 + s];
    }
#pragma unroll
    for (int mt = 0; mt < 2; ++mt)
#pragma unroll
      for (int r = 0; r < 4; ++r) c[mt][r] = 0.f;
    for (int j = tid; j < 32 * 136 / 2; j += 512) ((unsigned int*)hbuf)[j] = 0u;
    __syncthreads();
    for (int t = 0; t < NT; ++t) {
      int cur = t & 1, nxt = cur ^ 1;
      f4 acc[4][2];
#pragma unroll
      for (int g = 0; g < 4; ++g)
#pragma unroll
        for (int mt = 0; mt < 2; ++mt) acc[g][mt] = splat4(bb[g]);
#pragma unroll
      for (int mt = 0; mt < 2; ++mt) {
        h8 ax[4], ah[4];
#pragma unroll
        for (int kt = 0; kt < 4; ++kt) {
          ax[kt] = *(const h8*)&xbuf[t][mt * 16 + s][kt * 32 + q * 8];
          ah[kt] = *(const h8*)&hbuf[cur][mt * 16 + s][kt * 32 + q * 8];
        }
#pragma unroll
        for (int g = 0; g < 4; ++g)
#pragma unroll
          for (int kt = 0; kt < 4; ++kt) {
            acc[g][mt] = __builtin_amdgcn_mfma_f32_16x16x32_f16(ax[kt], wx[g][kt], acc[g][mt], 0, 0, 0);
            acc[g][mt] = __builtin_amdgcn_mfma_f32_16x16x32_f16(ah[kt], wh[g][kt], acc[g][mt], 0, 0, 0);
          }
      }
      h16 hv[2][4];
#pragma unroll
      for (int mt = 0; mt < 2; ++mt)
#pragma unroll
        for (int r = 0; r < 4; ++r) {
          float iv = acc[0][mt][r], fv = acc[1][mt][r];
          float gv = acc[2][mt][r], ov = acc[3][mt][r];
          float cc = sigf(fv) * c[mt][r] + sigf(iv) * tanhf_(gv);
          c[mt][r] = cc;
          hv[mt][r] = (h16)(sigf(ov) * tanhf_(cc));
        }
      __syncthreads();  // all frag reads done before x[t]/h writes
#pragma unroll
      for (int mt = 0; mt < 2; ++mt)
#pragma unroll
        for (int r = 0; r < 4; ++r) {
          int row = mt * 16 + q * 4 + r, col = w * 16 + s;
          xbuf[t][row][col] = hv[mt][r];   // x[t] for layer l+1
          hbuf[nxt][row][col] = hv[mt][r]; // h for t+1
        }
      __syncthreads();
    }
  }
  // ---- output head: each wave takes t=w (and t=w+8 for w<4) ----
  h8 wo[5][4];
  float bo[5];
  const h16* fco = wsh + OFF_FCOUT;
#pragma unroll
  for (int nt = 0; nt < 5; ++nt) {
#pragma unroll
    for (int kt = 0; kt < 4; ++kt)
      wo[nt][kt] = *(const h8*)(fco + (nt * 16 + kt * 4 + q) * 128 + s * 8);
    int col = nt * 16 + s;
    bo[nt] = (col < 75) ? fcoutb[col] : 0.f;
  }
  float* probst = (float*)&hbuf[0][0][0];  // [32][26] f32 stage
  int tcount = (w < 4) ? 2 : 1;
  for (int ti = 0; ti < tcount; ++ti) {
    int t = w + ti * 8;
#pragma unroll
    for (int mt = 0; mt < 2; ++mt) {
      h8 ax[4];
#pragma unroll
      for (int kt = 0; kt < 4; ++kt)
        ax[kt] = *(const h8*)&xbuf[t][mt * 16 + s][kt * 32 + q * 8];
#pragma unroll
      for (int nt = 0; nt < 5; ++nt) {
        f4 a = splat4(bo[nt]);
#pragma unroll
        for (int kt = 0; kt < 4; ++kt)
          a = __builtin_amdgcn_mfma_f32_16x16x32_f16(ax[kt], wo[nt][kt], a, 0, 0, 0);
        int col = nt * 16 + s;
#pragma unroll
        for (int r = 0; r < 4; ++r) {
          int row = mt * 16 + q * 4 + r;
          int b = brow + row;
          float v = a[r];
          if (col < 50)
            out[(size_t)b * 600 + (col >> 1) * 24 + t * 2 + (col & 1)] = v;
          if (t == 11 && col >= 50 && col < 75)
            probst[row * 26 + (col - 50)] = v;
        }
      }
    }
  }
  __syncthreads();
  if (tid < 32) {  // softmax over 25 modes, one batch row per thread
    float vals[25];
    float m = -1e30f;
#pragma unroll
    for (int j = 0; j < 25; ++j) { vals[j] = probst[tid * 26 + j]; m = vals[j] > m ? vals[j] : m; }
    float sum = 0.f;
#pragma unroll
    for (int j = 0; j < 25; ++j) {
      float e = __builtin_amdgcn_exp2f((vals[j] - m) * 1.4426950408889634f);
      vals[j] = e; sum += e;
    }
    float rs = 1.0f / sum;
    size_t pb = (size_t)4915200 + (size_t)(brow + tid) * 25;
#pragma unroll
    for (int j = 0; j < 25; ++j) out[pb + j] = vals[j] * rs;
  }
}

extern "C" void kernel_launch(void* const* d_in, const int* in_sizes, int n_in,
                              void* d_out, int out_size, void* d_ws, size_t ws_size,
                              hipStream_t stream) {
  const float* backbone = (const float*)d_in[0];
  const float* fcinW    = (const float*)d_in[1];
  const float* fcinb    = (const float*)d_in[2];
  const float* Wih      = (const float*)d_in[3];
  const float* Whh      = (const float*)d_in[4];
  const float* bih      = (const float*)d_in[5];
  const float* bhh      = (const float*)d_in[6];
  const float* fcoutW   = (const float*)d_in[7];
  const float* fcoutb   = (const float*)d_in[8];
  h16* wsh = (h16*)d_ws;
  float* wbias = (float*)((char*)d_ws + BYTE_BIAS);

  prep<<<922, 256, 0, stream>>>(fcinW, Wih, Whh, bih, bhh, fcoutW, wsh, wbias);
  kin<<<512, 256, 0, stream>>>(backbone, fcinb, wsh);
  lstm<<<256, 512, 0, stream>>>(wsh, wbias, fcoutb, (float*)d_out);
}

// Round 3
// 514.736 us; speedup vs baseline: 1.1995x; 1.0521x over previous
//
#include <hip/hip_runtime.h>

typedef _Float16 h16;
typedef _Float16 h4 __attribute__((ext_vector_type(4)));
typedef _Float16 h8 __attribute__((ext_vector_type(8)));
typedef float f4 __attribute__((ext_vector_type(4)));

#define NB 8192
#define NENC 4096
#define NH 128
#define NL 10
#define NT 12
#define PAD 136

// ---- workspace layout (element offsets in halfs unless noted) ----
#define OFF_FCIN 0                    // packed fc_in_W  [128 x 4096] fp16
#define SZ_FCIN (128*4096)
#define OFF_W (OFF_FCIN + SZ_FCIN)    // packed Wih/Whh  [10][2][512 x 128] fp16
#define SZ_W (10*2*512*128)
#define OFF_FCOUT (OFF_W + SZ_W)      // packed fc_out_W [80 x 128] fp16
#define SZ_FCOUT (80*128)
#define OFF_ENC (OFF_FCOUT + SZ_FCOUT) // enc (relu(fc_in)) [8192 x 128] fp16
#define SZ_ENC (8192*128)
#define OFF_GX0 (OFF_ENC + SZ_ENC)    // GX0 = enc@Wih0^T + b0, lane-layout fp16
#define SZ_GX0 (8192*512)
#define BYTE_BIAS ((OFF_GX0 + SZ_GX0)*2) // combined bias [10][512] f32 (byte offset)
// total ws usage: ~14.2 MB

__device__ __forceinline__ float sigf(float x) {
  float e = __builtin_amdgcn_exp2f(-1.4426950408889634f * x);
  return __builtin_amdgcn_rcpf(1.0f + e);
}
__device__ __forceinline__ float tanhf_(float x) {
  float e = __builtin_amdgcn_exp2f(-2.8853900817779268f * x);
  return 2.0f * __builtin_amdgcn_rcpf(1.0f + e) - 1.0f;
}
__device__ __forceinline__ f4 splat4(float v) { f4 r; r[0]=v; r[1]=v; r[2]=v; r[3]=v; return r; }
__device__ __forceinline__ h8 cvt8(float4 a, float4 b) {
  h8 r; r[0]=(h16)a.x; r[1]=(h16)a.y; r[2]=(h16)a.z; r[3]=(h16)a.w;
  r[4]=(h16)b.x; r[5]=(h16)b.y; r[6]=(h16)b.z; r[7]=(h16)b.w; return r;
}

// ---------------- prep: convert + pack weights (8 elems/thread) ----------------
__global__ __launch_bounds__(256) void prep(const float* __restrict__ fcinW,
                                            const float* __restrict__ Wih,
                                            const float* __restrict__ Whh,
                                            const float* __restrict__ bih,
                                            const float* __restrict__ bhh,
                                            const float* __restrict__ fcoutW,
                                            h16* __restrict__ wsh,
                                            float* __restrict__ wbias) {
  int idx = blockIdx.x * 256 + threadIdx.x;
  if (idx < 65536) {                          // fc_in_W [128][4096], Kd8=512
    int r = idx >> 9, k8 = idx & 511;
    const float* src = fcinW + r * 4096 + k8 * 8;
    h8 v = cvt8(*(const float4*)src, *(const float4*)(src + 4));
    *(h8*)(wsh + OFF_FCIN + (((r >> 4) * 512 + k8) * 128 + (r & 15) * 8)) = v;
  } else if (idx < 229376) {                  // Wih/Whh [10][512][128], Kd8=16
    int rel = idx - 65536;
    int l = rel >> 14, rr = rel & 16383;
    int ssel = rr >> 13, rk8 = rr & 8191;
    int r = rk8 >> 4, k8 = rk8 & 15;
    const float* src = (ssel ? Whh : Wih) + l * 65536 + r * 128 + k8 * 8;
    h8 v = cvt8(*(const float4*)src, *(const float4*)(src + 4));
    *(h8*)(wsh + OFF_W + (l * 2 + ssel) * 65536 +
           (((r >> 4) * 16 + k8) * 128 + (r & 15) * 8)) = v;
  } else if (idx < 230656) {                  // fc_out_W padded to [80][128]
    int rel = idx - 229376;
    int r = rel >> 4, k8 = rel & 15;
    h8 v;
    if (r < 75) {
      const float* src = fcoutW + r * 128 + k8 * 8;
      v = cvt8(*(const float4*)src, *(const float4*)(src + 4));
    } else {
      for (int j = 0; j < 8; ++j) v[j] = (h16)0.f;
    }
    *(h8*)(wsh + OFF_FCOUT + (((r >> 4) * 16 + k8) * 128 + (r & 15) * 8)) = v;
  } else if (idx < 235776) {
    int rel = idx - 230656;
    wbias[rel] = bih[rel] + bhh[rel];
  }
}

// ---------------- fc_in GEMM: enc = relu(A @ W^T + b), fp16 out ----------------
__global__ __launch_bounds__(256) void kin(const float* __restrict__ A,
                                           const float* __restrict__ bvec,
                                           h16* __restrict__ wsh) {
  const h16* Wp = wsh + OFF_FCIN;
  h16* ench = wsh + OFF_ENC;
  int tid = threadIdx.x;
  int w = tid >> 6, lane = tid & 63, s = lane & 15, q = lane >> 4;
  int m0 = blockIdx.x * 16;
  int c0 = w * 32 + s, c1 = c0 + 16;
  f4 acc0 = splat4(bvec[c0]);
  f4 acc1 = splat4(bvec[c1]);
  const float* arow = A + (size_t)(m0 + s) * NENC;
  const h16* wp0 = Wp + (w * 2 + 0) * (512 * 128) + s * 8;
  const h16* wp1 = Wp + (w * 2 + 1) * (512 * 128) + s * 8;
#pragma unroll 4
  for (int kb = 0; kb < 128; ++kb) {
    int k0 = kb * 32 + q * 8;
    float4 x0 = *(const float4*)(arow + k0);
    float4 x1 = *(const float4*)(arow + k0 + 4);
    h8 af = cvt8(x0, x1);
    h8 b0 = *(const h8*)(wp0 + (kb * 4 + q) * 128);
    h8 b1 = *(const h8*)(wp1 + (kb * 4 + q) * 128);
    acc0 = __builtin_amdgcn_mfma_f32_16x16x32_f16(af, b0, acc0, 0, 0, 0);
    acc1 = __builtin_amdgcn_mfma_f32_16x16x32_f16(af, b1, acc1, 0, 0, 0);
  }
#pragma unroll
  for (int r = 0; r < 4; ++r) {
    int b = m0 + q * 4 + r;
    float v0 = acc0[r]; v0 = v0 > 0.f ? v0 : 0.f;
    float v1 = acc1[r]; v1 = v1 > 0.f ? v1 : 0.f;
    ench[(size_t)b * NH + c0] = (h16)v0;
    ench[(size_t)b * NH + c1] = (h16)v1;
  }
}

// ---------------- kin2: GX0 = enc @ Wih0^T + b0 (t-invariant layer-0 x-GEMM) ----
// grid 2048 = [lb 256][mt 2][cg 4], block 256 (4 waves x 2 unit-blocks).
// Output layout matches lstm's lane order: [lb][W 8][g*2+mt][lane][r] fp16.
__global__ __launch_bounds__(256) void kin2(h16* __restrict__ wsh,
                                            const float* __restrict__ wbias) {
  int tid = threadIdx.x;
  int w2 = tid >> 6, lane = tid & 63, s = lane & 15, q = lane >> 4;
  int bid = blockIdx.x;
  int lb = bid >> 3, mt = (bid >> 2) & 1, cg = bid & 3;
  const h16* ench = wsh + OFF_ENC;
  const h16* wih0 = wsh + OFF_W;
  h16* gx0 = wsh + OFF_GX0;
  const h16* arow = ench + (size_t)(lb * 32 + mt * 16 + s) * NH;
  h8 ax[4];
#pragma unroll
  for (int kt = 0; kt < 4; ++kt) ax[kt] = *(const h8*)(arow + kt * 32 + q * 8);
#pragma unroll
  for (int ti = 0; ti < 2; ++ti) {
    int W = w2 * 2 + ti;
    int rb = cg * 8 + W;
    f4 acc = splat4(wbias[cg * 128 + W * 16 + s]);
#pragma unroll
    for (int kt = 0; kt < 4; ++kt) {
      h8 b = *(const h8*)(wih0 + (rb * 16 + kt * 4 + q) * 128 + s * 8);
      acc = __builtin_amdgcn_mfma_f32_16x16x32_f16(ax[kt], b, acc, 0, 0, 0);
    }
    h4 st; st[0] = (h16)acc[0]; st[1] = (h16)acc[1]; st[2] = (h16)acc[2]; st[3] = (h16)acc[3];
    *(h4*)(gx0 + ((((size_t)lb * 8 + W) * 8 + cg * 2 + mt) * 64 + lane) * 4) = st;
  }
}

// ---------------- persistent LSTM + output head ----------------
// grid 256 = 1 WG/CU, block 512 = 8 waves (2/SIMD), 32 batch rows/WG.
// 13-slot LDS ring: layer l at step t reads x from slot (t+12-l)%13, reads
// h(t-1) from slot (t+10-l)%13 (its own write of last step - no hbuf), writes
// h(t) to slot (t+11-l)%13. Slots never alias within a step -> ONE barrier
// per (l,t) and 8 LDS writes/wave (was 2 barriers, 16 writes).
// Layer 0 uses register-resident GX0 (t-invariant); t=0 skips h-GEMM (h=0).
__global__ __launch_bounds__(512, 2) void lstm(h16* __restrict__ wsh,
                                               const float* __restrict__ wbias,
                                               const float* __restrict__ fcoutb,
                                               float* __restrict__ out) {
  __shared__ h16 ring[13][32][PAD];   // 113152 B
  __shared__ float probst[32 * 26];
  int tid = threadIdx.x;
  int w = tid >> 6, lane = tid & 63, s = lane & 15, q = lane >> 4;
  int brow = blockIdx.x * 32;
  h8 wx[4][4], wh[4][4];
  float bb[4];
  float c[2][4];

  // ---------- layer 0: acc starts from GX0 (regs), no x-MFMAs ----------
  {
    const h16* whh = wsh + OFF_W + 65536;
#pragma unroll
    for (int g = 0; g < 4; ++g)
#pragma unroll
      for (int kt = 0; kt < 4; ++kt)
        wh[g][kt] = *(const h8*)(whh + (((g * 8 + w) * 16 + kt * 4 + q) * 128) + s * 8);
    f4 gx[4][2];
    const h16* gxp = wsh + OFF_GX0 + ((size_t)blockIdx.x * 8 + w) * 8 * 256 + (size_t)lane * 4;
#pragma unroll
    for (int g = 0; g < 4; ++g)
#pragma unroll
      for (int mt = 0; mt < 2; ++mt) {
        h4 v = *(const h4*)(gxp + (g * 2 + mt) * 256);
        f4 a; a[0] = (float)v[0]; a[1] = (float)v[1]; a[2] = (float)v[2]; a[3] = (float)v[3];
        gx[g][mt] = a;
      }
#pragma unroll
    for (int mt = 0; mt < 2; ++mt)
#pragma unroll
      for (int r = 0; r < 4; ++r) c[mt][r] = 0.f;
    for (int t = 0; t < NT; ++t) {
      __syncthreads();
      int rw = t + 11; if (rw >= 13) rw -= 13;
      int rh = t + 10; if (rh >= 13) rh -= 13;
      f4 acc[4][2];
#pragma unroll
      for (int g = 0; g < 4; ++g)
#pragma unroll
        for (int mt = 0; mt < 2; ++mt) acc[g][mt] = gx[g][mt];
      if (t > 0) {
#pragma unroll
        for (int mt = 0; mt < 2; ++mt) {
          h8 ah[4];
#pragma unroll
          for (int kt = 0; kt < 4; ++kt)
            ah[kt] = *(const h8*)&ring[rh][mt * 16 + s][kt * 32 + q * 8];
#pragma unroll
          for (int g = 0; g < 4; ++g)
#pragma unroll
            for (int kt = 0; kt < 4; ++kt)
              acc[g][mt] = __builtin_amdgcn_mfma_f32_16x16x32_f16(ah[kt], wh[g][kt], acc[g][mt], 0, 0, 0);
        }
      }
#pragma unroll
      for (int mt = 0; mt < 2; ++mt)
#pragma unroll
        for (int r = 0; r < 4; ++r) {
          float iv = acc[0][mt][r], fv = acc[1][mt][r];
          float gv = acc[2][mt][r], ov = acc[3][mt][r];
          float cc = sigf(fv) * c[mt][r] + sigf(iv) * tanhf_(gv);
          c[mt][r] = cc;
          ring[rw][mt * 16 + q * 4 + r][w * 16 + s] = (h16)(sigf(ov) * tanhf_(cc));
        }
    }
  }
  // ---------- layers 1..9 ----------
  for (int l = 1; l < NL; ++l) {
    const h16* wih = wsh + OFF_W + (size_t)(l * 2) * 65536;
    const h16* whh = wih + 65536;
#pragma unroll
    for (int g = 0; g < 4; ++g) {
#pragma unroll
      for (int kt = 0; kt < 4; ++kt) {
        int off = (((g * 8 + w) * 16 + kt * 4 + q) * 128) + s * 8;
        wx[g][kt] = *(const h8*)(wih + off);
        wh[g][kt] = *(const h8*)(whh + off);
      }
      bb[g] = wbias[l * 512 + g * 128 + w * 16 + s];
    }
#pragma unroll
    for (int mt = 0; mt < 2; ++mt)
#pragma unroll
      for (int r = 0; r < 4; ++r) c[mt][r] = 0.f;
    int base = 12 - l;
    for (int t = 0; t < NT; ++t) {
      __syncthreads();
      int rr = t + base; if (rr >= 13) rr -= 13;
      int rw = rr - 1; if (rw < 0) rw += 13;
      int rh = rw - 1; if (rh < 0) rh += 13;
      f4 acc[4][2];
#pragma unroll
      for (int g = 0; g < 4; ++g)
#pragma unroll
        for (int mt = 0; mt < 2; ++mt) acc[g][mt] = splat4(bb[g]);
#pragma unroll
      for (int mt = 0; mt < 2; ++mt) {
        h8 ax[4];
#pragma unroll
        for (int kt = 0; kt < 4; ++kt)
          ax[kt] = *(const h8*)&ring[rr][mt * 16 + s][kt * 32 + q * 8];
#pragma unroll
        for (int g = 0; g < 4; ++g)
#pragma unroll
          for (int kt = 0; kt < 4; ++kt)
            acc[g][mt] = __builtin_amdgcn_mfma_f32_16x16x32_f16(ax[kt], wx[g][kt], acc[g][mt], 0, 0, 0);
      }
      if (t > 0) {
#pragma unroll
        for (int mt = 0; mt < 2; ++mt) {
          h8 ah[4];
#pragma unroll
          for (int kt = 0; kt < 4; ++kt)
            ah[kt] = *(const h8*)&ring[rh][mt * 16 + s][kt * 32 + q * 8];
#pragma unroll
          for (int g = 0; g < 4; ++g)
#pragma unroll
            for (int kt = 0; kt < 4; ++kt)
              acc[g][mt] = __builtin_amdgcn_mfma_f32_16x16x32_f16(ah[kt], wh[g][kt], acc[g][mt], 0, 0, 0);
        }
      }
#pragma unroll
      for (int mt = 0; mt < 2; ++mt)
#pragma unroll
        for (int r = 0; r < 4; ++r) {
          float iv = acc[0][mt][r], fv = acc[1][mt][r];
          float gv = acc[2][mt][r], ov = acc[3][mt][r];
          float cc = sigf(fv) * c[mt][r] + sigf(iv) * tanhf_(gv);
          c[mt][r] = cc;
          ring[rw][mt * 16 + q * 4 + r][w * 16 + s] = (h16)(sigf(ov) * tanhf_(cc));
        }
    }
  }
  // ---- output head: layer-9 h(t) lives in ring slot (t+2)%13 ----
  __syncthreads();
  h8 wo[5][4];
  float bo[5];
  const h16* fco = wsh + OFF_FCOUT;
#pragma unroll
  for (int nt = 0; nt < 5; ++nt) {
#pragma unroll
    for (int kt = 0; kt < 4; ++kt)
      wo[nt][kt] = *(const h8*)(fco + (nt * 16 + kt * 4 + q) * 128 + s * 8);
    int col = nt * 16 + s;
    bo[nt] = (col < 75) ? fcoutb[col] : 0.f;
  }
  int tcount = (w < 4) ? 2 : 1;
  for (int ti = 0; ti < tcount; ++ti) {
    int t = w + ti * 8;
    int sl = t + 2; if (sl >= 13) sl -= 13;
#pragma unroll
    for (int mt = 0; mt < 2; ++mt) {
      h8 ax[4];
#pragma unroll
      for (int kt = 0; kt < 4; ++kt)
        ax[kt] = *(const h8*)&ring[sl][mt * 16 + s][kt * 32 + q * 8];
#pragma unroll
      for (int nt = 0; nt < 5; ++nt) {
        f4 a = splat4(bo[nt]);
#pragma unroll
        for (int kt = 0; kt < 4; ++kt)
          a = __builtin_amdgcn_mfma_f32_16x16x32_f16(ax[kt], wo[nt][kt], a, 0, 0, 0);
        int col = nt * 16 + s;
#pragma unroll
        for (int r = 0; r < 4; ++r) {
          int row = mt * 16 + q * 4 + r;
          int b = brow + row;
          float v = a[r];
          if (col < 50)
            out[(size_t)b * 600 + (col >> 1) * 24 + t * 2 + (col & 1)] = v;
          if (t == 11 && col >= 50 && col < 75)
            probst[row * 26 + (col - 50)] = v;
        }
      }
    }
  }
  __syncthreads();
  if (tid < 32) {
    float vals[25];
    float m = -1e30f;
#pragma unroll
    for (int j = 0; j < 25; ++j) { vals[j] = probst[tid * 26 + j]; m = vals[j] > m ? vals[j] : m; }
    float sum = 0.f;
#pragma unroll
    for (int j = 0; j < 25; ++j) {
      float e = __builtin_amdgcn_exp2f((vals[j] - m) * 1.4426950408889634f);
      vals[j] = e; sum += e;
    }
    float rs = 1.0f / sum;
    size_t pb = (size_t)4915200 + (size_t)(brow + tid) * 25;
#pragma unroll
    for (int j = 0; j < 25; ++j) out[pb + j] = vals[j] * rs;
  }
}

extern "C" void kernel_launch(void* const* d_in, const int* in_sizes, int n_in,
                              void* d_out, int out_size, void* d_ws, size_t ws_size,
                              hipStream_t stream) {
  const float* backbone = (const float*)d_in[0];
  const float* fcinW    = (const float*)d_in[1];
  const float* fcinb    = (const float*)d_in[2];
  const float* Wih      = (const float*)d_in[3];
  const float* Whh      = (const float*)d_in[4];
  const float* bih      = (const float*)d_in[5];
  const float* bhh      = (const float*)d_in[6];
  const float* fcoutW   = (const float*)d_in[7];
  const float* fcoutb   = (const float*)d_in[8];
  h16* wsh = (h16*)d_ws;
  float* wbias = (float*)((char*)d_ws + BYTE_BIAS);

  prep<<<922, 256, 0, stream>>>(fcinW, Wih, Whh, bih, bhh, fcoutW, wsh, wbias);
  kin<<<512, 256, 0, stream>>>(backbone, fcinb, wsh);
  kin2<<<2048, 256, 0, stream>>>(wsh, wbias);
  lstm<<<256, 512, 0, stream>>>(wsh, wbias, fcoutb, (float*)d_out);
}